// Round 1
// baseline (1742.485 us; speedup 1.0000x reference)
//
#include <hip/hip_runtime.h>
#include <hip/hip_bf16.h>

#define BB  64
#define JJ  2048
#define DI  16
#define KC  32
#define DOO 32
#define NKO 1024   // KC*DOO

typedef __bf16 bf16;
typedef __attribute__((ext_vector_type(8))) __bf16 bf16x8;
typedef __attribute__((ext_vector_type(4))) float f32x4;

// One fused routing pass:
//   for each j in this block's range: hat[b, (k,o)] = X_j @ W_j (MFMA, bf16 in / f32 acc)
//   mode 0: s += hat / 32                      (uniform softmax of b=0)
//   mode 1: logits = vsum . hat ; softmax over K ; s += c * hat
// Block: 512 threads = 8 waves; wave w owns ko slice [w*128, (w+1)*128) (4 capsules).
// b handled in 4 chunks of 16 (MFMA M=16). s kept in registers, partials written bf16.
__global__ __launch_bounds__(512, 2)
void caps_pass(const float* __restrict__ X, const float* __restrict__ Wg,
               const float* __restrict__ vsum, bf16* __restrict__ partial,
               int mode, int Jc)
{
    // W fragments: 64 tiles * (32 lanes * 8 bf16), tile stride padded 256->264 to break
    // the 32-way bank collision on the staging ds_write_b16s.
    __shared__ __align__(16) bf16  Wlds[64 * 264];
    __shared__ __align__(16) bf16  xlds[BB * DI];
    __shared__ float clds[4][16][KC];     // per-chunk logits -> softmax c
    __shared__ __align__(16) float zeroLds[8];

    const int tid  = threadIdx.x;
    const int w    = tid >> 6;        // wave 0..7
    const int lane = tid & 63;
    const int g    = lane >> 4;       // 0..3
    const int c0   = lane & 15;

    if (tid < 8) zeroLds[tid] = 0.0f;

    const f32x4 ZV = {};
    f32x4 sacc[4][8];
#pragma unroll
    for (int c = 0; c < 4; ++c)
#pragma unroll
        for (int t = 0; t < 8; ++t) sacc[c][t] = ZV;

    const int j0 = blockIdx.x * Jc;
    int jend = j0 + Jc; if (jend > JJ) jend = JJ;

    for (int j = j0; j < jend; ++j) {
        // ---- stage W_j (16384 f32, fully coalesced float4) -> bf16 fragment layout ----
        const float* Wj = Wg + (size_t)j * (KC * DI * DOO);
#pragma unroll
        for (int it = 0; it < 8; ++it) {
            int f = (it * 512 + tid) * 4;
            const float4 v4 = *reinterpret_cast<const float4*>(Wj + f);
            int kc  = f >> 9;          // capsule k
            int rem = f & 511;
            int i   = rem >> 5;        // 0..15
            int o   = rem & 31;        // multiple of 4
            int n   = kc * 32 + o;     // ko column
            int t   = n >> 4;          // tile
            int cc  = n & 15;          // col within tile (cc..cc+3 same tile)
            int idx = t * 264 + ((i >> 3) << 7) + (i & 7);
            Wlds[idx + (cc + 0) * 8] = (bf16)v4.x;
            Wlds[idx + (cc + 1) * 8] = (bf16)v4.y;
            Wlds[idx + (cc + 2) * 8] = (bf16)v4.z;
            Wlds[idx + (cc + 3) * 8] = (bf16)v4.w;
        }
        // ---- stage x_j : [64 b][16 i] bf16 ----
#pragma unroll
        for (int it = 0; it < 2; ++it) {
            int f = it * 512 + tid;           // < 1024
            int b = f >> 4, i = f & 15;
            xlds[f] = (bf16)X[(size_t)b * (JJ * DI) + (size_t)j * DI + i];
        }
        __syncthreads();

#pragma unroll
        for (int c = 0; c < 4; ++c) {
            // A fragment: A[row=c0][k=g*8+e] = x[b = c*16+row][i = k] ; k>=16 -> 0
            bf16x8 afr;
            {
                const bf16* ap = (lane < 32)
                    ? (xlds + ((c * 16 + c0) * 16 + g * 8))
                    : reinterpret_cast<const bf16*>(zeroLds);
                afr = *reinterpret_cast<const bf16x8*>(ap);
            }
            f32x4 acch[8];
#pragma unroll
            for (int t = 0; t < 8; ++t) {
                const bf16* bp = (lane < 32)
                    ? (Wlds + (w * 8 + t) * 264 + lane * 8)
                    : reinterpret_cast<const bf16*>(zeroLds);
                bf16x8 bfr = *reinterpret_cast<const bf16x8*>(bp);
                acch[t] = __builtin_amdgcn_mfma_f32_16x16x32_bf16(afr, bfr, ZV, 0, 0, 0);
            }

            if (mode == 0) {
#pragma unroll
                for (int t = 0; t < 8; ++t)
#pragma unroll
                    for (int r = 0; r < 4; ++r)
                        sacc[c][t][r] += acch[t][r] * 0.03125f;
            } else {
                // logits: lane partial over its column c0; o = (t&1)*16 + c0
                float vv0[4][4], vv1[4][4];
                const float* vb = vsum + ((c * 16 + g * 4) * KC + w * 4) * DOO + c0;
#pragma unroll
                for (int r = 0; r < 4; ++r)
#pragma unroll
                    for (int kk = 0; kk < 4; ++kk) {
                        vv0[r][kk] = vb[(r * KC + kk) * DOO];
                        vv1[r][kk] = vb[(r * KC + kk) * DOO + 16];
                    }
                float lp[4][4];
#pragma unroll
                for (int r = 0; r < 4; ++r)
#pragma unroll
                    for (int kk = 0; kk < 4; ++kk)
                        lp[r][kk] = acch[2 * kk][r] * vv0[r][kk]
                                  + acch[2 * kk + 1][r] * vv1[r][kk];
                // reduce over the 16 columns (lanes sharing g)
#pragma unroll
                for (int m = 1; m < 16; m <<= 1)
#pragma unroll
                    for (int r = 0; r < 4; ++r)
#pragma unroll
                        for (int kk = 0; kk < 4; ++kk)
                            lp[r][kk] += __shfl_xor(lp[r][kk], m, 16);
                if (c0 == 0) {
#pragma unroll
                    for (int r = 0; r < 4; ++r)
#pragma unroll
                        for (int kk = 0; kk < 4; ++kk)
                            clds[c][g * 4 + r][w * 4 + kk] = lp[r][kk];
                }
                __syncthreads();
                // softmax over K=32 per (b_local): thread (bl = tid>>5, k = tid&31)
                {
                    int bl = tid >> 5;
                    int k  = tid & 31;
                    float xv = clds[c][bl][k];
                    float mx = xv;
#pragma unroll
                    for (int m = 16; m >= 1; m >>= 1)
                        mx = fmaxf(mx, __shfl_xor(mx, m, 32));
                    float ev = __expf(xv - mx);
                    float sm = ev;
#pragma unroll
                    for (int m = 16; m >= 1; m >>= 1)
                        sm += __shfl_xor(sm, m, 32);
                    clds[c][bl][k] = ev / sm;
                }
                __syncthreads();
#pragma unroll
                for (int t = 0; t < 8; ++t) {
                    const int kk = t >> 1;
#pragma unroll
                    for (int r = 0; r < 4; ++r) {
                        float cw = clds[c][g * 4 + r][w * 4 + kk];  // broadcast read
                        sacc[c][t][r] += cw * acch[t][r];
                    }
                }
            }
        }
        __syncthreads();   // protect Wlds/xlds for next j
    }

    // ---- write bf16 partials: partial[blk][b*1024 + ko] ----
    bf16* pout = partial + (size_t)blockIdx.x * (BB * NKO);
#pragma unroll
    for (int c = 0; c < 4; ++c)
#pragma unroll
        for (int t = 0; t < 8; ++t)
#pragma unroll
            for (int r = 0; r < 4; ++r) {
                int b  = c * 16 + g * 4 + r;
                int ko = w * 128 + t * 16 + c0;
                pout[b * NKO + ko] = (bf16)sacc[c][t][r];
            }
}

// Sum partials over P blocks, squash over o (32 consecutive lanes = one (b,k) row),
// then update vsum (set/add) and optionally write the final output.
__global__ __launch_bounds__(256)
void caps_reduce(const bf16* __restrict__ partial, float* __restrict__ vsum,
                 float* __restrict__ out, int P, int vmode, int wout)
{
    const int e = blockIdx.x * 256 + threadIdx.x;   // < 65536
    float a0 = 0.f, a1 = 0.f, a2 = 0.f, a3 = 0.f;
    int p = 0;
    for (; p + 4 <= P; p += 4) {
        a0 += (float)partial[(size_t)(p + 0) * 65536 + e];
        a1 += (float)partial[(size_t)(p + 1) * 65536 + e];
        a2 += (float)partial[(size_t)(p + 2) * 65536 + e];
        a3 += (float)partial[(size_t)(p + 3) * 65536 + e];
    }
    for (; p < P; ++p) a0 += (float)partial[(size_t)p * 65536 + e];
    float s = (a0 + a1) + (a2 + a3);

    float s2 = s * s;
#pragma unroll
    for (int m = 16; m >= 1; m >>= 1) s2 += __shfl_xor(s2, m, 32);
    float scale = s2 / (1.0f + s2) / sqrtf(s2 + 1e-7f);
    float v = scale * s;

    if (vmode == 0)      vsum[e] = v;
    else if (vmode == 1) vsum[e] += v;
    if (wout)            out[e] = v;
}

extern "C" void kernel_launch(void* const* d_in, const int* in_sizes, int n_in,
                              void* d_out, int out_size, void* d_ws, size_t ws_size,
                              hipStream_t stream)
{
    const float* X  = (const float*)d_in[0];   // [64, 2048, 16] f32
    const float* Wg = (const float*)d_in[1];   // [2048, 32, 16, 32] f32
    float* out = (float*)d_out;                // [64, 32, 32] f32

    const size_t SLICE = (size_t)BB * NKO;     // 65536 elements
    const size_t VS_BYTES = SLICE * sizeof(float);

    int P = 256;
    if (ws_size < (size_t)P * SLICE * 2 + VS_BYTES) {
        size_t pp = (ws_size > VS_BYTES) ? (ws_size - VS_BYTES) / (SLICE * 2) : 1;
        P = (int)pp;
        if (P < 1) P = 1;
        if (P > 256) P = 256;
    }
    const int Jc = (JJ + P - 1) / P;

    bf16*  partial = (bf16*)d_ws;
    float* vsum    = (float*)((char*)d_ws + (size_t)P * SLICE * 2);

    // routing iteration 0: uniform c = 1/32
    caps_pass<<<dim3(P), dim3(512), 0, stream>>>(X, Wg, vsum, partial, 0, Jc);
    caps_reduce<<<dim3(256), dim3(256), 0, stream>>>(partial, vsum, out, P, 0, 0); // vsum = v0
    // routing iteration 1: logits = v0 . hat
    caps_pass<<<dim3(P), dim3(512), 0, stream>>>(X, Wg, vsum, partial, 1, Jc);
    caps_reduce<<<dim3(256), dim3(256), 0, stream>>>(partial, vsum, out, P, 1, 0); // vsum += v1
    // routing iteration 2: logits = (v0+v1) . hat ; write output
    caps_pass<<<dim3(P), dim3(512), 0, stream>>>(X, Wg, vsum, partial, 1, Jc);
    caps_reduce<<<dim3(256), dim3(256), 0, stream>>>(partial, vsum, out, P, 2, 1);
}

// Round 2
// 1120.566 us; speedup vs baseline: 1.5550x; 1.5550x over previous
//
#include <hip/hip_runtime.h>
#include <hip/hip_bf16.h>

#define BB  64
#define JJ  2048
#define DI  16
#define KC  32
#define DOO 32
#define NKO 1024   // KC*DOO

typedef __bf16 bf16;
typedef __attribute__((ext_vector_type(8))) __bf16 bf16x8;
typedef __attribute__((ext_vector_type(4))) float f32x4;

// ---------------- prep: W f32 [J][K][Di][Do] -> bf16 MFMA B-fragment layout ----------------
// Wfrag[((j*64 + t)*32 + l)*8 + e] = W[j][ko>>5][i=(l>>4)*8+e][ko&31],  ko = t*16 + (l&15)
// (l = 0..31; k-rows 16..31 are the zero half of the 16x16x32 fragment, never stored)
__global__ __launch_bounds__(256)
void prep_w(const float* __restrict__ W, bf16* __restrict__ Wfrag)
{
    int flat = blockIdx.x * 256 + threadIdx.x;        // < 2048*64*32 = 4194304
    int l  = flat & 31;
    int t  = (flat >> 5) & 63;
    int j  = flat >> 11;
    int i0 = (l >> 4) * 8;
    int ko = t * 16 + (l & 15);
    const float* src = W + (size_t)j * 16384 + (size_t)(ko >> 5) * 512 + (size_t)i0 * 32 + (ko & 31);
    bf16x8 o8;
#pragma unroll
    for (int e = 0; e < 8; ++e) o8[e] = (bf16)src[e * 32];
    *reinterpret_cast<bf16x8*>(Wfrag + (size_t)flat * 8) = o8;
}

// ---------------- prep: X f32 [B][J][Di] -> bf16 MFMA A-fragment layout ----------------
// Xfrag[((j*4 + c)*32 + l)*8 + e] = X[b = c*16 + (l&15)][j][i = (l>>4)*8 + e]
__global__ __launch_bounds__(256)
void prep_x(const float* __restrict__ X, bf16* __restrict__ Xfrag)
{
    int flat = blockIdx.x * 256 + threadIdx.x;        // < 2048*4*32 = 262144
    int l = flat & 31;
    int c = (flat >> 5) & 3;
    int j = flat >> 7;
    int b = c * 16 + (l & 15);
    int i0 = (l >> 4) * 8;
    const float* src = X + ((size_t)b * JJ + j) * DI + i0;
    bf16x8 o8;
#pragma unroll
    for (int e = 0; e < 8; ++e) o8[e] = (bf16)src[e];
    *reinterpret_cast<bf16x8*>(Xfrag + (size_t)flat * 8) = o8;
}

// ---------------- fused routing pass ----------------
// Block: 512 threads = 8 waves; wave w owns ko tiles w*8..w*8+7 (128 cols). b in 4 chunks of 16.
// mode 0: s += hat/32 (no barriers). mode 1: 3 barriers/j: logits -> softmax -> accumulate.
__global__ __launch_bounds__(512, 2)
void caps_pass2(const bf16* __restrict__ Xfrag, const bf16* __restrict__ Wfrag,
                const float* __restrict__ Xf, const float* __restrict__ Wf,
                const float* __restrict__ vsum, bf16* __restrict__ partial,
                int mode, int Jc, int useFrag)
{
    __shared__ float clds[64][33];      // logits / softmax weights [b][k]
    __shared__ bf16  stg[16][1032];     // output transpose staging (one b-chunk)

    const int tid  = threadIdx.x;
    const int w    = tid >> 6;
    const int lane = tid & 63;
    const int g    = lane >> 4;
    const int c0   = lane & 15;
    const int l5   = lane & 31;
    const bool act = lane < 32;         // fragment-holding half of the wave

    const f32x4 ZV = {};
    const bf16x8 ZB = {};
    f32x4 sacc[4][8];
#pragma unroll
    for (int c = 0; c < 4; ++c)
#pragma unroll
        for (int t = 0; t < 8; ++t) sacc[c][t] = ZV;

    const int j0 = blockIdx.x * Jc;
    int jend = j0 + Jc; if (jend > JJ) jend = JJ;

    for (int j = j0; j < jend; ++j) {
        if (mode == 1) __syncthreads();   // protect clds from previous j's phase C reads

        // ---- load this wave's 8 B-fragments (coalesced 16B/lane) ----
        bf16x8 bfr[8];
#pragma unroll
        for (int t = 0; t < 8; ++t) bfr[t] = ZB;
        if (act) {
            if (useFrag) {
                const bf16* bp = Wfrag + ((size_t)j * 64 + w * 8) * 256 + l5 * 8;
#pragma unroll
                for (int t = 0; t < 8; ++t)
                    bfr[t] = *reinterpret_cast<const bf16x8*>(bp + t * 256);
            } else {
#pragma unroll
                for (int t = 0; t < 8; ++t) {
                    int ko = (w * 8 + t) * 16 + (l5 & 15);
                    const float* s = Wf + (size_t)j * 16384 + (size_t)(ko >> 5) * 512
                                   + (size_t)((l5 >> 4) * 8) * 32 + (ko & 31);
                    bf16x8 tmp;
#pragma unroll
                    for (int e = 0; e < 8; ++e) tmp[e] = (bf16)s[e * 32];
                    bfr[t] = tmp;
                }
            }
        }

        auto load_afr = [&](int c) -> bf16x8 {
            bf16x8 a = ZB;
            if (act) {
                if (useFrag) {
                    a = *reinterpret_cast<const bf16x8*>(Xfrag + (((size_t)j * 4 + c) * 32 + l5) * 8);
                } else {
                    const float* s = Xf + ((size_t)(c * 16 + (l5 & 15)) * JJ + j) * DI + (l5 >> 4) * 8;
#pragma unroll
                    for (int e = 0; e < 8; ++e) a[e] = (bf16)s[e];
                }
            }
            return a;
        };

        if (mode == 1) {
            // ---- phase A: logits ----
#pragma unroll
            for (int c = 0; c < 4; ++c) {
                bf16x8 afr = load_afr(c);
                float v16[16];
#pragma unroll
                for (int grp = 0; grp < 2; ++grp) {
                    f32x4 acch[4];
#pragma unroll
                    for (int t2 = 0; t2 < 4; ++t2)
                        acch[t2] = __builtin_amdgcn_mfma_f32_16x16x32_bf16(afr, bfr[grp * 4 + t2], ZV, 0, 0, 0);
#pragma unroll
                    for (int t2 = 0; t2 < 4; t2 += 2) {
                        int kk = grp * 2 + (t2 >> 1);
#pragma unroll
                        for (int r = 0; r < 4; ++r) {
                            const float* vb = vsum + ((size_t)(c * 16 + g * 4 + r) * KC + (w * 4 + kk)) * DOO + c0;
                            v16[r * 4 + kk] = acch[t2][r] * vb[0] + acch[t2 + 1][r] * vb[16];
                        }
                    }
                }
                // fold-butterfly: 16 partial sums x 16 lanes -> lane c0 holds q=c0
                int cnt = 16;
#pragma unroll
                for (int m = 1; m < 16; m <<= 1) {
                    int half = cnt >> 1;
                    bool up = (c0 & m) != 0;
#pragma unroll
                    for (int u = 0; u < 8; ++u) {
                        if (u < half) {
                            float sendv = up ? v16[2 * u]     : v16[2 * u + 1];
                            float keepv = up ? v16[2 * u + 1] : v16[2 * u];
                            v16[u] = keepv + __shfl_xor(sendv, m, 64);
                        }
                    }
                    cnt = half;
                }
                clds[c * 16 + g * 4 + ((c0 >> 2) & 3)][w * 4 + (c0 & 3)] = v16[0];
            }
            __syncthreads();
            // ---- phase B: softmax over K=32 per b-row (8 threads/row, 4 k each) ----
            {
                int row = tid >> 3;
                int k0  = (tid & 7) * 4;
                float x0 = clds[row][k0], x1 = clds[row][k0 + 1];
                float x2 = clds[row][k0 + 2], x3 = clds[row][k0 + 3];
                float mx = fmaxf(fmaxf(x0, x1), fmaxf(x2, x3));
#pragma unroll
                for (int m = 1; m < 8; m <<= 1) mx = fmaxf(mx, __shfl_xor(mx, m, 64));
                float e0 = __expf(x0 - mx), e1 = __expf(x1 - mx);
                float e2 = __expf(x2 - mx), e3 = __expf(x3 - mx);
                float sm = (e0 + e1) + (e2 + e3);
#pragma unroll
                for (int m = 1; m < 8; m <<= 1) sm += __shfl_xor(sm, m, 64);
                float inv = 1.0f / sm;
                clds[row][k0] = e0 * inv; clds[row][k0 + 1] = e1 * inv;
                clds[row][k0 + 2] = e2 * inv; clds[row][k0 + 3] = e3 * inv;
            }
            __syncthreads();
        }

        // ---- phase C: weighted accumulate (recompute MFMAs) ----
#pragma unroll
        for (int c = 0; c < 4; ++c) {
            bf16x8 afr = load_afr(c);
            float cwv[4][4];
            if (mode == 1) {
#pragma unroll
                for (int r = 0; r < 4; ++r)
#pragma unroll
                    for (int kk = 0; kk < 4; ++kk)
                        cwv[r][kk] = clds[c * 16 + g * 4 + r][w * 4 + kk];
            }
#pragma unroll
            for (int grp = 0; grp < 2; ++grp) {
                f32x4 acch[4];
#pragma unroll
                for (int t2 = 0; t2 < 4; ++t2)
                    acch[t2] = __builtin_amdgcn_mfma_f32_16x16x32_bf16(afr, bfr[grp * 4 + t2], ZV, 0, 0, 0);
#pragma unroll
                for (int t2 = 0; t2 < 4; ++t2) {
                    int t = grp * 4 + t2;
                    int kk = t >> 1;
#pragma unroll
                    for (int r = 0; r < 4; ++r) {
                        float cw = (mode == 1) ? cwv[r][kk] : 0.03125f;
                        sacc[c][t][r] += cw * acch[t2][r];
                    }
                }
            }
        }
    }

    // ---- epilogue: transpose through LDS, coalesced bf16 partial store ----
    bf16* pout = partial + (size_t)blockIdx.x * (BB * NKO);
#pragma unroll
    for (int c = 0; c < 4; ++c) {
        __syncthreads();
#pragma unroll
        for (int t = 0; t < 8; ++t)
#pragma unroll
            for (int r = 0; r < 4; ++r)
                stg[g * 4 + r][w * 128 + t * 16 + c0] = (bf16)sacc[c][t][r];
        __syncthreads();
        int row = tid >> 5;
        int cl  = (tid & 31) * 8;
#pragma unroll
        for (int ch = 0; ch < 4; ++ch) {
            bf16x8 v8 = *reinterpret_cast<const bf16x8*>(&stg[row][cl + ch * 256]);
            *reinterpret_cast<bf16x8*>(pout + (size_t)(c * 16 + row) * NKO + cl + ch * 256) = v8;
        }
    }
}

// ---------------- reduce partials + squash -> v ; update vsum ----------------
__global__ __launch_bounds__(256)
void caps_reduce2(const bf16* __restrict__ partial, float* __restrict__ vsum,
                  float* __restrict__ out, int P, int vmode, int wout)
{
    int t8 = blockIdx.x * 256 + threadIdx.x;          // < 8192 ; owns 8 consecutive o
    const bf16* base = partial + (size_t)t8 * 8;
    float acc[8];
#pragma unroll
    for (int e = 0; e < 8; ++e) acc[e] = 0.0f;
    for (int p = 0; p < P; ++p) {
        bf16x8 v8 = *reinterpret_cast<const bf16x8*>(base + (size_t)p * 65536);
#pragma unroll
        for (int e = 0; e < 8; ++e) acc[e] += (float)v8[e];
    }
    float s2 = 0.0f;
#pragma unroll
    for (int e = 0; e < 8; ++e) s2 += acc[e] * acc[e];
    s2 += __shfl_xor(s2, 1, 64);
    s2 += __shfl_xor(s2, 2, 64);                      // 4 threads = one (b,k) row of 32 o
    float scale = s2 / (1.0f + s2) / sqrtf(s2 + 1e-7f);
    int e0 = t8 * 8;
#pragma unroll
    for (int e = 0; e < 8; ++e) {
        float v = scale * acc[e];
        if (vmode == 0)      vsum[e0 + e]  = v;
        else if (vmode == 1) vsum[e0 + e] += v;
        if (wout)            out[e0 + e]   = v;
    }
}

extern "C" void kernel_launch(void* const* d_in, const int* in_sizes, int n_in,
                              void* d_out, int out_size, void* d_ws, size_t ws_size,
                              hipStream_t stream)
{
    const float* X  = (const float*)d_in[0];   // [64, 2048, 16] f32
    const float* Wg = (const float*)d_in[1];   // [2048, 32, 16, 32] f32
    float* out = (float*)d_out;                // [64, 32, 32] f32

    const size_t SLICE   = (size_t)BB * NKO;               // 65536
    const size_t WFRAG_B = (size_t)JJ * 64 * 32 * 8 * 2;   // 67108864
    const size_t XFRAG_B = (size_t)JJ * 4 * 32 * 8 * 2;    // 4194304
    const size_t VS_B    = SLICE * sizeof(float);          // 262144

    int P = 256;
    int useFrag = 1;
    bf16 *Wfrag = nullptr, *Xfrag = nullptr, *partial = nullptr;
    float* vsum = nullptr;

    if (ws_size >= WFRAG_B + XFRAG_B + VS_B + (size_t)P * SLICE * 2) {
        Wfrag   = (bf16*)d_ws;
        Xfrag   = (bf16*)((char*)d_ws + WFRAG_B);
        vsum    = (float*)((char*)d_ws + WFRAG_B + XFRAG_B);
        partial = (bf16*)((char*)d_ws + WFRAG_B + XFRAG_B + VS_B);
    } else {
        useFrag = 0;
        size_t avail = (ws_size > VS_B) ? (ws_size - VS_B) / (SLICE * 2) : 1;
        P = (int)avail; if (P < 1) P = 1; if (P > 256) P = 256;
        vsum    = (float*)d_ws;
        partial = (bf16*)((char*)d_ws + VS_B);
    }
    const int Jc = (JJ + P - 1) / P;

    if (useFrag) {
        prep_w<<<dim3(16384), dim3(256), 0, stream>>>(Wg, Wfrag);
        prep_x<<<dim3(1024),  dim3(256), 0, stream>>>(X,  Xfrag);
    }

    // routing iteration 0: uniform c = 1/32
    caps_pass2<<<dim3(P), dim3(512), 0, stream>>>(Xfrag, Wfrag, X, Wg, vsum, partial, 0, Jc, useFrag);
    caps_reduce2<<<dim3(32), dim3(256), 0, stream>>>(partial, vsum, out, P, 0, 0);   // vsum = v0
    // routing iteration 1
    caps_pass2<<<dim3(P), dim3(512), 0, stream>>>(Xfrag, Wfrag, X, Wg, vsum, partial, 1, Jc, useFrag);
    caps_reduce2<<<dim3(32), dim3(256), 0, stream>>>(partial, vsum, out, P, 1, 0);   // vsum += v1
    // routing iteration 2 (writes output)
    caps_pass2<<<dim3(P), dim3(512), 0, stream>>>(Xfrag, Wfrag, X, Wg, vsum, partial, 1, Jc, useFrag);
    caps_reduce2<<<dim3(32), dim3(256), 0, stream>>>(partial, vsum, out, P, 2, 1);
}

// Round 3
// 985.686 us; speedup vs baseline: 1.7678x; 1.1368x over previous
//
#include <hip/hip_runtime.h>
#include <hip/hip_bf16.h>

#define BB  64
#define JJ  2048
#define DI  16
#define KC  32
#define DOO 32
#define NKO 1024   // KC*DOO

typedef __bf16 bf16;
typedef __attribute__((ext_vector_type(8))) __bf16 bf16x8;
typedef __attribute__((ext_vector_type(4))) __bf16 bf16x4;
typedef __attribute__((ext_vector_type(4))) float f32x4;

// ---------------- prep: W f32 [J][K][Di][Do] -> bf16 MFMA B-fragment layout ----------------
// Wfrag[((j*64 + t)*32 + l)*8 + e] = W[j][ko>>5][i=(l>>4)*8+e][ko&31],  ko = t*16 + (l&15)
__global__ __launch_bounds__(256)
void prep_w(const float* __restrict__ W, bf16* __restrict__ Wfrag)
{
    int flat = blockIdx.x * 256 + threadIdx.x;        // < 2048*64*32 = 4194304
    int l  = flat & 31;
    int t  = (flat >> 5) & 63;
    int j  = flat >> 11;
    int i0 = (l >> 4) * 8;
    int ko = t * 16 + (l & 15);
    const float* src = W + (size_t)j * 16384 + (size_t)(ko >> 5) * 512 + (size_t)i0 * 32 + (ko & 31);
    bf16x8 o8;
#pragma unroll
    for (int e = 0; e < 8; ++e) o8[e] = (bf16)src[e * 32];
    *reinterpret_cast<bf16x8*>(Wfrag + (size_t)flat * 8) = o8;
}

// ---------------- prep: X f32 [B][J][Di] -> bf16 MFMA A-fragment layout ----------------
// Xfrag[((j*4 + c)*32 + l)*8 + e] = X[b = c*16 + (l&15)][j][i = (l>>4)*8 + e]
__global__ __launch_bounds__(256)
void prep_x(const float* __restrict__ X, bf16* __restrict__ Xfrag)
{
    int flat = blockIdx.x * 256 + threadIdx.x;        // < 2048*4*32 = 262144
    int l = flat & 31;
    int c = (flat >> 5) & 3;
    int j = flat >> 7;
    int b = c * 16 + (l & 15);
    int i0 = (l >> 4) * 8;
    const float* src = X + ((size_t)b * JJ + j) * DI + i0;
    bf16x8 o8;
#pragma unroll
    for (int e = 0; e < 8; ++e) o8[e] = (bf16)src[e];
    *reinterpret_cast<bf16x8*>(Xfrag + (size_t)flat * 8) = o8;
}

// ---------------- fused routing pass (16 waves, 4 tiles/wave -> sacc = 64 VGPR) ----------------
// Wave w owns ko tiles w*4..w*4+3 (k = w*2, w*2+1). b in 4 chunks of 16 (MFMA M dim).
// mode 0: sacc = MFMA C-in accumulate, 2 j's packed per MFMA (K=32 = 2*Di), no barriers.
// mode 1: per j: phase A (logits) -> barrier -> phase B (softmax K=32) -> barrier ->
//         phase C (recompute MFMA, VALU-weighted accumulate). clds double-buffered.
__global__ __launch_bounds__(1024, 4)
void caps_pass3(const bf16* __restrict__ Xfrag, const bf16* __restrict__ Wfrag,
                const float* __restrict__ Xf, const float* __restrict__ Wf,
                const float* __restrict__ vsum, bf16* __restrict__ partial,
                int mode, int Jc, int useFrag)
{
    __shared__ float clds[2][64][33];

    const int tid  = threadIdx.x;
    const int w    = tid >> 6;        // 0..15
    const int lane = tid & 63;
    const int g    = lane >> 4;
    const int c0   = lane & 15;
    const int l5   = lane & 31;
    const bool hi  = lane >= 32;

    const f32x4 ZV = {};
    const bf16x8 ZB = {};

    f32x4 sacc[4][4];
#pragma unroll
    for (int c = 0; c < 4; ++c)
#pragma unroll
        for (int t2 = 0; t2 < 4; ++t2) sacc[c][t2] = ZV;

    const int j0 = blockIdx.x * Jc;
    int jend = j0 + Jc; if (jend > JJ) jend = JJ;

    // fragment loaders (l5-based address is always valid; hi lanes zeroed when unpacked)
    auto load_bfr_one = [&](int j, int t2) -> bf16x8 {
        if (useFrag)
            return *reinterpret_cast<const bf16x8*>(Wfrag + (((size_t)j * 64 + w * 4 + t2) * 32 + l5) * 8);
        int ko = (w * 4 + t2) * 16 + (l5 & 15);
        const float* s = Wf + (size_t)j * 16384 + (size_t)(ko >> 5) * 512
                       + (size_t)((l5 >> 4) * 8) * 32 + (ko & 31);
        bf16x8 tmp;
#pragma unroll
        for (int e = 0; e < 8; ++e) tmp[e] = (bf16)s[e * 32];
        return tmp;
    };
    auto load_afr_one = [&](int j, int c) -> bf16x8 {
        if (useFrag)
            return *reinterpret_cast<const bf16x8*>(Xfrag + (((size_t)j * 4 + c) * 32 + l5) * 8);
        const float* s = Xf + ((size_t)(c * 16 + (l5 & 15)) * JJ + j) * DI + (l5 >> 4) * 8;
        bf16x8 tmp;
#pragma unroll
        for (int e = 0; e < 8; ++e) tmp[e] = (bf16)s[e];
        return tmp;
    };

    if (mode == 0) {
        int j = j0;
        if (useFrag) {
            for (; j + 1 < jend; j += 2) {          // packed: lanes>=32 carry j+1 (K rows 16..31)
                const int jsel = j + (hi ? 1 : 0);
                bf16x8 bfr[4];
#pragma unroll
                for (int t2 = 0; t2 < 4; ++t2)
                    bfr[t2] = *reinterpret_cast<const bf16x8*>(
                        Wfrag + (((size_t)jsel * 64 + w * 4 + t2) * 32 + l5) * 8);
#pragma unroll
                for (int c = 0; c < 4; ++c) {
                    bf16x8 afr = *reinterpret_cast<const bf16x8*>(
                        Xfrag + (((size_t)jsel * 4 + c) * 32 + l5) * 8);
#pragma unroll
                    for (int t2 = 0; t2 < 4; ++t2)
                        sacc[c][t2] = __builtin_amdgcn_mfma_f32_16x16x32_bf16(afr, bfr[t2], sacc[c][t2], 0, 0, 0);
                }
            }
        }
        for (; j < jend; ++j) {                     // tail / fallback (K rows 16..31 zero)
            bf16x8 bfr[4];
#pragma unroll
            for (int t2 = 0; t2 < 4; ++t2) { bfr[t2] = load_bfr_one(j, t2); if (hi) bfr[t2] = ZB; }
#pragma unroll
            for (int c = 0; c < 4; ++c) {
                bf16x8 afr = load_afr_one(j, c); if (hi) afr = ZB;
#pragma unroll
                for (int t2 = 0; t2 < 4; ++t2)
                    sacc[c][t2] = __builtin_amdgcn_mfma_f32_16x16x32_bf16(afr, bfr[t2], sacc[c][t2], 0, 0, 0);
            }
        }
    } else {
        for (int j = j0; j < jend; ++j) {
            const int pb = j & 1;
            bf16x8 bfr[4];
#pragma unroll
            for (int t2 = 0; t2 < 4; ++t2) { bfr[t2] = load_bfr_one(j, t2); if (hi) bfr[t2] = ZB; }

            // ---- phase A: logits ----
#pragma unroll
            for (int c = 0; c < 4; ++c) {
                bf16x8 afr = load_afr_one(j, c); if (hi) afr = ZB;
                float lp[8];
#pragma unroll
                for (int kk = 0; kk < 2; ++kk) {
                    f32x4 a0 = __builtin_amdgcn_mfma_f32_16x16x32_bf16(afr, bfr[2 * kk], ZV, 0, 0, 0);
                    f32x4 a1 = __builtin_amdgcn_mfma_f32_16x16x32_bf16(afr, bfr[2 * kk + 1], ZV, 0, 0, 0);
                    const float* vb = vsum + ((size_t)(c * 16 + g * 4) * KC + (w * 2 + kk)) * DOO + c0;
#pragma unroll
                    for (int r = 0; r < 4; ++r)
                        lp[r * 2 + kk] = a0[r] * vb[(size_t)r * KC * DOO]
                                       + a1[r] * vb[(size_t)r * KC * DOO + 16];
                }
                // fold-butterfly over the 16 o-lanes: 8 partials -> 1 total per lane
                {
                    bool up1 = (c0 & 1) != 0;
#pragma unroll
                    for (int u = 0; u < 4; ++u) {
                        float sendv = up1 ? lp[2 * u] : lp[2 * u + 1];
                        float keepv = up1 ? lp[2 * u + 1] : lp[2 * u];
                        lp[u] = keepv + __shfl_xor(sendv, 1, 64);
                    }
                    bool up2 = (c0 & 2) != 0;
#pragma unroll
                    for (int u = 0; u < 2; ++u) {
                        float sendv = up2 ? lp[2 * u] : lp[2 * u + 1];
                        float keepv = up2 ? lp[2 * u + 1] : lp[2 * u];
                        lp[u] = keepv + __shfl_xor(sendv, 2, 64);
                    }
                    bool up4 = (c0 & 4) != 0;
                    {
                        float sendv = up4 ? lp[0] : lp[1];
                        float keepv = up4 ? lp[1] : lp[0];
                        lp[0] = keepv + __shfl_xor(sendv, 4, 64);
                    }
                    lp[0] += __shfl_xor(lp[0], 8, 64);
                }
                // lane c0 holds total for flat idx c0&7 = r*2+kk
                if (c0 < 8)
                    clds[pb][c * 16 + g * 4 + ((c0 & 7) >> 1)][w * 2 + (c0 & 1)] = lp[0];
            }
            __syncthreads();

            // ---- phase B: softmax over K=32 per b-row (16 threads/row, 2 k each) ----
            {
                int row = tid >> 4, q = tid & 15;
                float x0 = clds[pb][row][2 * q], x1 = clds[pb][row][2 * q + 1];
                float mx = fmaxf(x0, x1);
#pragma unroll
                for (int m = 1; m < 16; m <<= 1) mx = fmaxf(mx, __shfl_xor(mx, m, 64));
                float e0 = __expf(x0 - mx), e1 = __expf(x1 - mx);
                float sm = e0 + e1;
#pragma unroll
                for (int m = 1; m < 16; m <<= 1) sm += __shfl_xor(sm, m, 64);
                float inv = 1.0f / sm;
                clds[pb][row][2 * q] = e0 * inv;
                clds[pb][row][2 * q + 1] = e1 * inv;
            }
            __syncthreads();

            // ---- phase C: weighted accumulate (recompute MFMA) ----
#pragma unroll
            for (int c = 0; c < 4; ++c) {
                bf16x8 afr = load_afr_one(j, c); if (hi) afr = ZB;
                float cw[4][2];
#pragma unroll
                for (int r = 0; r < 4; ++r)
#pragma unroll
                    for (int kk = 0; kk < 2; ++kk)
                        cw[r][kk] = clds[pb][c * 16 + g * 4 + r][w * 2 + kk];
#pragma unroll
                for (int t2 = 0; t2 < 4; ++t2) {
                    f32x4 ah = __builtin_amdgcn_mfma_f32_16x16x32_bf16(afr, bfr[t2], ZV, 0, 0, 0);
                    const int kk = t2 >> 1;
#pragma unroll
                    for (int r = 0; r < 4; ++r)
                        sacc[c][t2][r] += cw[r][kk] * ah[r];
                }
            }
        }
    }

    // ---- epilogue: MFMA-natural-order partial store (coalesced 8B/lane) ----
    bf16* pout = partial + (size_t)blockIdx.x * (BB * NKO);
    const float esc = (mode == 0) ? 0.03125f : 1.0f;
#pragma unroll
    for (int c = 0; c < 4; ++c)
#pragma unroll
        for (int t2 = 0; t2 < 4; ++t2) {
            bf16x4 o4;
#pragma unroll
            for (int r = 0; r < 4; ++r) o4[r] = (bf16)(sacc[c][t2][r] * esc);
            *reinterpret_cast<bf16x4*>(pout + (((size_t)c * 64 + (w * 4 + t2)) * 64 + lane) * 4) = o4;
        }
}

// ---------------- reduce partials (natural order) + squash -> v ; update vsum ----------------
// Thread group of 64 <-> (c, k); lane holds (g, c0); 4 r's x 2 o-halves per thread.
__global__ __launch_bounds__(256)
void caps_reduce3(const bf16* __restrict__ partial, float* __restrict__ vsum,
                  float* __restrict__ out, int P, int vmode, int wout)
{
    int gt   = blockIdx.x * 256 + threadIdx.x;   // < 8192
    int grp  = gt >> 6;                           // 0..127
    int lane = gt & 63;
    int c = grp >> 5, k = grp & 31;
    int g = lane >> 4, c0 = lane & 15;

    const bf16* b0 = partial + ((size_t)(c * 64 + k * 2) * 64 + lane) * 4;
    float a0[4] = {0.f, 0.f, 0.f, 0.f}, a1[4] = {0.f, 0.f, 0.f, 0.f};
    for (int p = 0; p < P; ++p) {
        bf16x4 v0 = *reinterpret_cast<const bf16x4*>(b0 + (size_t)p * 65536);
        bf16x4 v1 = *reinterpret_cast<const bf16x4*>(b0 + 256 + (size_t)p * 65536);
#pragma unroll
        for (int r = 0; r < 4; ++r) { a0[r] += (float)v0[r]; a1[r] += (float)v1[r]; }
    }
#pragma unroll
    for (int r = 0; r < 4; ++r) {
        float s2 = a0[r] * a0[r] + a1[r] * a1[r];
#pragma unroll
        for (int m = 1; m < 16; m <<= 1) s2 += __shfl_xor(s2, m, 64);
        float scale = s2 / (1.0f + s2) / sqrtf(s2 + 1e-7f);
        int b  = c * 16 + g * 4 + r;
        int e0 = (b * KC + k) * DOO + c0;
        float v0o = scale * a0[r], v1o = scale * a1[r];
        if (vmode == 0)      { vsum[e0] = v0o;  vsum[e0 + 16] = v1o; }
        else if (vmode == 1) { vsum[e0] += v0o; vsum[e0 + 16] += v1o; }
        if (wout)            { out[e0] = v0o;   out[e0 + 16] = v1o; }
    }
}

extern "C" void kernel_launch(void* const* d_in, const int* in_sizes, int n_in,
                              void* d_out, int out_size, void* d_ws, size_t ws_size,
                              hipStream_t stream)
{
    const float* X  = (const float*)d_in[0];   // [64, 2048, 16] f32
    const float* Wg = (const float*)d_in[1];   // [2048, 32, 16, 32] f32
    float* out = (float*)d_out;                // [64, 32, 32] f32

    const size_t SLICE   = (size_t)BB * NKO;               // 65536
    const size_t WFRAG_B = (size_t)JJ * 64 * 32 * 8 * 2;   // 67108864
    const size_t XFRAG_B = (size_t)JJ * 4 * 32 * 8 * 2;    // 4194304
    const size_t VS_B    = SLICE * sizeof(float);          // 262144

    int P = 256;
    int useFrag = 1;
    bf16 *Wfrag = nullptr, *Xfrag = nullptr, *partial = nullptr;
    float* vsum = nullptr;

    if (ws_size >= WFRAG_B + XFRAG_B + VS_B + (size_t)P * SLICE * 2) {
        Wfrag   = (bf16*)d_ws;
        Xfrag   = (bf16*)((char*)d_ws + WFRAG_B);
        vsum    = (float*)((char*)d_ws + WFRAG_B + XFRAG_B);
        partial = (bf16*)((char*)d_ws + WFRAG_B + XFRAG_B + VS_B);
    } else {
        useFrag = 0;
        size_t avail = (ws_size > VS_B) ? (ws_size - VS_B) / (SLICE * 2) : 1;
        P = (int)avail; if (P < 1) P = 1; if (P > 256) P = 256;
        vsum    = (float*)d_ws;
        partial = (bf16*)((char*)d_ws + VS_B);
    }
    const int Jc = (JJ + P - 1) / P;

    if (useFrag) {
        prep_w<<<dim3(16384), dim3(256), 0, stream>>>(Wg, Wfrag);
        prep_x<<<dim3(1024),  dim3(256), 0, stream>>>(X,  Xfrag);
    }

    // routing iteration 0: uniform c = 1/32
    caps_pass3<<<dim3(P), dim3(1024), 0, stream>>>(Xfrag, Wfrag, X, Wg, vsum, partial, 0, Jc, useFrag);
    caps_reduce3<<<dim3(32), dim3(256), 0, stream>>>(partial, vsum, out, P, 0, 0);   // vsum = v0
    // routing iteration 1
    caps_pass3<<<dim3(P), dim3(1024), 0, stream>>>(Xfrag, Wfrag, X, Wg, vsum, partial, 1, Jc, useFrag);
    caps_reduce3<<<dim3(32), dim3(256), 0, stream>>>(partial, vsum, out, P, 1, 0);   // vsum += v1
    // routing iteration 2 (writes output)
    caps_pass3<<<dim3(P), dim3(1024), 0, stream>>>(Xfrag, Wfrag, X, Wg, vsum, partial, 1, Jc, useFrag);
    caps_reduce3<<<dim3(32), dim3(256), 0, stream>>>(partial, vsum, out, P, 2, 1);
}

// Round 4
// 303.795 us; speedup vs baseline: 5.7357x; 3.2446x over previous
//
#include <hip/hip_runtime.h>
#include <hip/hip_bf16.h>

#define BB  64
#define JJ  2048
#define DI  16
#define KC  32
#define DOO 32
#define NKO 1024   // KC*DOO

typedef __bf16 bf16;
typedef __attribute__((ext_vector_type(8))) __bf16 bf16x8;
typedef __attribute__((ext_vector_type(4))) __bf16 bf16x4;
typedef __attribute__((ext_vector_type(4))) float f32x4;

// ---------------- prep: W f32 [J][K][Di][Do] -> bf16 MFMA B-fragment layout ----------------
// Wfrag[((j*64 + t)*32 + l)*8 + e] = W[j][ko>>5][i=(l>>4)*8+e][ko&31],  ko = t*16 + (l&15)
__global__ __launch_bounds__(256)
void prep_w(const float* __restrict__ W, bf16* __restrict__ Wfrag)
{
    int flat = blockIdx.x * 256 + threadIdx.x;        // < 2048*64*32 = 4194304
    int l  = flat & 31;
    int t  = (flat >> 5) & 63;
    int j  = flat >> 11;
    int i0 = (l >> 4) * 8;
    int ko = t * 16 + (l & 15);
    const float* src = W + (size_t)j * 16384 + (size_t)(ko >> 5) * 512 + (size_t)i0 * 32 + (ko & 31);
    bf16x8 o8;
#pragma unroll
    for (int e = 0; e < 8; ++e) o8[e] = (bf16)src[e * 32];
    *reinterpret_cast<bf16x8*>(Wfrag + (size_t)flat * 8) = o8;
}

// ---------------- prep: X f32 [B][J][Di] -> bf16 MFMA A-fragment layout ----------------
// Xfrag[((j*4 + c)*32 + l)*8 + e] = X[b = c*16 + (l&15)][j][i = (l>>4)*8 + e]
__global__ __launch_bounds__(256)
void prep_x(const float* __restrict__ X, bf16* __restrict__ Xfrag)
{
    int flat = blockIdx.x * 256 + threadIdx.x;        // < 2048*4*32 = 262144
    int l = flat & 31;
    int c = (flat >> 5) & 3;
    int j = flat >> 7;
    int b = c * 16 + (l & 15);
    int i0 = (l >> 4) * 8;
    const float* src = X + ((size_t)b * JJ + j) * DI + i0;
    bf16x8 o8;
#pragma unroll
    for (int e = 0; e < 8; ++e) o8[e] = (bf16)src[e];
    *reinterpret_cast<bf16x8*>(Xfrag + (size_t)flat * 8) = o8;
}

// ---------------- routing iteration 0 (uniform c=1/32): pure MFMA stream ----------------
// grid (P, 4): blockIdx.y = b-chunk c. 16 waves; wave w owns ko tiles w*4..w*4+3.
// Packed: lanes>=32 carry j+1 (MFMA K rows 16..31). acc = 16 VGPR via MFMA C-in.
template<int UF>
__global__ __launch_bounds__(1024, 8)
void caps_init(const bf16* __restrict__ Xfrag, const bf16* __restrict__ Wfrag,
               const float* __restrict__ Xf, const float* __restrict__ Wf,
               bf16* __restrict__ partial, int Jc)
{
    const int tid  = threadIdx.x;
    const int w    = tid >> 6;
    const int lane = tid & 63;
    const int l5   = lane & 31;
    const bool hi  = lane >= 32;
    const int c    = blockIdx.y;

    const f32x4 ZV = {};
    const bf16x8 ZB = {};
    f32x4 acc[4] = {ZV, ZV, ZV, ZV};

    const int j0 = blockIdx.x * Jc;
    int jend = j0 + Jc; if (jend > JJ) jend = JJ;

    int j = j0;
    if constexpr (UF) {
        for (; j + 1 < jend; j += 2) {
            const int js = j + (hi ? 1 : 0);
            bf16x8 afr = *reinterpret_cast<const bf16x8*>(
                Xfrag + (((size_t)js * 4 + c) * 32 + l5) * 8);
#pragma unroll
            for (int t2 = 0; t2 < 4; ++t2) {
                bf16x8 bfr = *reinterpret_cast<const bf16x8*>(
                    Wfrag + (((size_t)js * 64 + w * 4 + t2) * 32 + l5) * 8);
                acc[t2] = __builtin_amdgcn_mfma_f32_16x16x32_bf16(afr, bfr, acc[t2], 0, 0, 0);
            }
        }
    }
    for (; j < jend; ++j) {    // tail (odd Jc) / raw-f32 fallback: K rows 16..31 zero
        bf16x8 afr = ZB;
        if (!hi) {
            if constexpr (UF) {
                afr = *reinterpret_cast<const bf16x8*>(Xfrag + (((size_t)j * 4 + c) * 32 + l5) * 8);
            } else {
                const float* s = Xf + ((size_t)(c * 16 + (l5 & 15)) * JJ + j) * DI + (l5 >> 4) * 8;
#pragma unroll
                for (int e = 0; e < 8; ++e) afr[e] = (bf16)s[e];
            }
        }
#pragma unroll
        for (int t2 = 0; t2 < 4; ++t2) {
            bf16x8 bfr = ZB;
            if (!hi) {
                if constexpr (UF) {
                    bfr = *reinterpret_cast<const bf16x8*>(
                        Wfrag + (((size_t)j * 64 + w * 4 + t2) * 32 + l5) * 8);
                } else {
                    int ko = (w * 4 + t2) * 16 + (l5 & 15);
                    const float* s = Wf + (size_t)j * 16384 + (size_t)(ko >> 5) * 512
                                   + (size_t)((l5 >> 4) * 8) * 32 + (ko & 31);
#pragma unroll
                    for (int e = 0; e < 8; ++e) bfr[e] = (bf16)s[e * 32];
                }
            }
            acc[t2] = __builtin_amdgcn_mfma_f32_16x16x32_bf16(afr, bfr, acc[t2], 0, 0, 0);
        }
    }

    bf16* pout = partial + (size_t)blockIdx.x * (BB * NKO);
#pragma unroll
    for (int t2 = 0; t2 < 4; ++t2) {
        bf16x4 o4;
#pragma unroll
        for (int r = 0; r < 4; ++r) o4[r] = (bf16)(acc[t2][r] * 0.03125f);
        *reinterpret_cast<bf16x4*>(pout + (((size_t)c * 64 + (w * 4 + t2)) * 64 + lane) * 4) = o4;
    }
}

// ---------------- routing iteration 1/2: logits -> softmax -> weighted accumulate ----------------
// hat[4] (16 VGPR) held across phases; phase C is pure VALU (no MFMA recompute, no re-read).
template<int UF>
__global__ __launch_bounds__(1024, 8)
void caps_route(const bf16* __restrict__ Xfrag, const bf16* __restrict__ Wfrag,
                const float* __restrict__ Xf, const float* __restrict__ Wf,
                const float* __restrict__ vsum, bf16* __restrict__ partial, int Jc)
{
    __shared__ float clds[2][16][33];

    const int tid  = threadIdx.x;
    const int w    = tid >> 6;
    const int lane = tid & 63;
    const int g    = lane >> 4;
    const int c0   = lane & 15;
    const int l5   = lane & 31;
    const bool lo  = lane < 32;
    const int c    = blockIdx.y;

    const f32x4 ZV = {};
    const bf16x8 ZB = {};
    f32x4 sacc[4] = {ZV, ZV, ZV, ZV};

    const int j0 = blockIdx.x * Jc;
    int jend = j0 + Jc; if (jend > JJ) jend = JJ;

    // j-invariant vsum base: values at vbase[r*1024 + kk*32 + half*16]
    const float* vbase = vsum + ((size_t)(c * 16 + g * 4) * KC + w * 2) * DOO + c0;

    for (int j = j0; j < jend; ++j) {
        const int pb = j & 1;

        // ---- phase A: hat + logit partials ----
        bf16x8 afr = ZB;
        if (lo) {
            if constexpr (UF) {
                afr = *reinterpret_cast<const bf16x8*>(Xfrag + (((size_t)j * 4 + c) * 32 + l5) * 8);
            } else {
                const float* s = Xf + ((size_t)(c * 16 + (l5 & 15)) * JJ + j) * DI + (l5 >> 4) * 8;
#pragma unroll
                for (int e = 0; e < 8; ++e) afr[e] = (bf16)s[e];
            }
        }
        f32x4 hat[4];
        float lp[8] = {0.f, 0.f, 0.f, 0.f, 0.f, 0.f, 0.f, 0.f};
#pragma unroll
        for (int t2 = 0; t2 < 4; ++t2) {
            bf16x8 bfr = ZB;
            if (lo) {
                if constexpr (UF) {
                    bfr = *reinterpret_cast<const bf16x8*>(
                        Wfrag + (((size_t)j * 64 + w * 4 + t2) * 32 + l5) * 8);
                } else {
                    int ko = (w * 4 + t2) * 16 + (l5 & 15);
                    const float* s = Wf + (size_t)j * 16384 + (size_t)(ko >> 5) * 512
                                   + (size_t)((l5 >> 4) * 8) * 32 + (ko & 31);
#pragma unroll
                    for (int e = 0; e < 8; ++e) bfr[e] = (bf16)s[e * 32];
                }
            }
            hat[t2] = __builtin_amdgcn_mfma_f32_16x16x32_bf16(afr, bfr, ZV, 0, 0, 0);
            const int kk = t2 >> 1, hf = t2 & 1;
#pragma unroll
            for (int r = 0; r < 4; ++r)
                lp[r * 2 + kk] += hat[t2][r] * vbase[(size_t)r * (KC * DOO) + kk * 32 + hf * 16];
        }
        // fold-butterfly over the 16 o-lanes: lane c0<8 ends with total of element c0 (r=c0>>1, kk=c0&1)
        {
            bool up1 = (c0 & 1) != 0;
#pragma unroll
            for (int u = 0; u < 4; ++u) {
                float sv = up1 ? lp[2 * u] : lp[2 * u + 1];
                float kv = up1 ? lp[2 * u + 1] : lp[2 * u];
                lp[u] = kv + __shfl_xor(sv, 1, 64);
            }
            bool up2 = (c0 & 2) != 0;
#pragma unroll
            for (int u = 0; u < 2; ++u) {
                float sv = up2 ? lp[2 * u] : lp[2 * u + 1];
                float kv = up2 ? lp[2 * u + 1] : lp[2 * u];
                lp[u] = kv + __shfl_xor(sv, 2, 64);
            }
            bool up4 = (c0 & 4) != 0;
            {
                float sv = up4 ? lp[0] : lp[1];
                float kv = up4 ? lp[1] : lp[0];
                lp[0] = kv + __shfl_xor(sv, 4, 64);
            }
            lp[0] += __shfl_xor(lp[0], 8, 64);
            if (c0 < 8)
                clds[pb][g * 4 + (c0 >> 1)][w * 2 + (c0 & 1)] = lp[0];
        }
        __syncthreads();

        // ---- phase B: softmax over K=32; wave w handles b-row w (hi half duplicates) ----
        {
            int k = lane & 31;
            float xv = clds[pb][w][k];
            float mx = xv;
#pragma unroll
            for (int m = 1; m < 32; m <<= 1) mx = fmaxf(mx, __shfl_xor(mx, m, 64));
            float ev = __expf(xv - mx);
            float sm = ev;
#pragma unroll
            for (int m = 1; m < 32; m <<= 1) sm += __shfl_xor(sm, m, 64);
            clds[pb][w][k] = ev / sm;
        }
        __syncthreads();

        // ---- phase C: weighted accumulate from held hat (pure VALU) ----
        float cw[4][2];
#pragma unroll
        for (int r = 0; r < 4; ++r)
#pragma unroll
            for (int kk = 0; kk < 2; ++kk)
                cw[r][kk] = clds[pb][g * 4 + r][w * 2 + kk];
#pragma unroll
        for (int t2 = 0; t2 < 4; ++t2)
#pragma unroll
            for (int r = 0; r < 4; ++r)
                sacc[t2][r] += cw[r][t2 >> 1] * hat[t2][r];
    }

    bf16* pout = partial + (size_t)blockIdx.x * (BB * NKO);
#pragma unroll
    for (int t2 = 0; t2 < 4; ++t2) {
        bf16x4 o4;
#pragma unroll
        for (int r = 0; r < 4; ++r) o4[r] = (bf16)sacc[t2][r];
        *reinterpret_cast<bf16x4*>(pout + (((size_t)c * 64 + (w * 4 + t2)) * 64 + lane) * 4) = o4;
    }
}

// ---------------- reduce partials (natural order) + squash -> v ; update vsum ----------------
__global__ __launch_bounds__(256)
void caps_reduce3(const bf16* __restrict__ partial, float* __restrict__ vsum,
                  float* __restrict__ out, int P, int vmode, int wout)
{
    int gt   = blockIdx.x * 256 + threadIdx.x;   // < 8192
    int grp  = gt >> 6;                           // 0..127 = (c, k)
    int lane = gt & 63;
    int c = grp >> 5, k = grp & 31;
    int g = lane >> 4, c0 = lane & 15;

    const bf16* b0 = partial + ((size_t)(c * 64 + k * 2) * 64 + lane) * 4;
    float a0[4] = {0.f, 0.f, 0.f, 0.f}, a1[4] = {0.f, 0.f, 0.f, 0.f};
    for (int p = 0; p < P; ++p) {
        bf16x4 v0 = *reinterpret_cast<const bf16x4*>(b0 + (size_t)p * 65536);
        bf16x4 v1 = *reinterpret_cast<const bf16x4*>(b0 + 256 + (size_t)p * 65536);
#pragma unroll
        for (int r = 0; r < 4; ++r) { a0[r] += (float)v0[r]; a1[r] += (float)v1[r]; }
    }
#pragma unroll
    for (int r = 0; r < 4; ++r) {
        float s2 = a0[r] * a0[r] + a1[r] * a1[r];
#pragma unroll
        for (int m = 1; m < 16; m <<= 1) s2 += __shfl_xor(s2, m, 64);
        float scale = s2 / (1.0f + s2) / sqrtf(s2 + 1e-7f);
        int b  = c * 16 + g * 4 + r;
        int e0 = (b * KC + k) * DOO + c0;
        float v0o = scale * a0[r], v1o = scale * a1[r];
        if (vmode == 0)      { vsum[e0] = v0o;  vsum[e0 + 16] = v1o; }
        else if (vmode == 1) { vsum[e0] += v0o; vsum[e0 + 16] += v1o; }
        if (wout)            { out[e0] = v0o;   out[e0 + 16] = v1o; }
    }
}

extern "C" void kernel_launch(void* const* d_in, const int* in_sizes, int n_in,
                              void* d_out, int out_size, void* d_ws, size_t ws_size,
                              hipStream_t stream)
{
    const float* X  = (const float*)d_in[0];   // [64, 2048, 16] f32
    const float* Wg = (const float*)d_in[1];   // [2048, 32, 16, 32] f32
    float* out = (float*)d_out;                // [64, 32, 32] f32

    const size_t SLICE   = (size_t)BB * NKO;               // 65536 elements
    const size_t WFRAG_B = (size_t)JJ * 64 * 32 * 8 * 2;   // 67108864
    const size_t XFRAG_B = (size_t)JJ * 4 * 32 * 8 * 2;    // 4194304
    const size_t VS_B    = SLICE * sizeof(float);          // 262144

    int P = 128;
    int useFrag = 1;
    bf16 *Wfrag = nullptr, *Xfrag = nullptr, *partial = nullptr;
    float* vsum = nullptr;

    if (ws_size >= WFRAG_B + XFRAG_B + VS_B + (size_t)P * SLICE * 2) {
        Wfrag   = (bf16*)d_ws;
        Xfrag   = (bf16*)((char*)d_ws + WFRAG_B);
        vsum    = (float*)((char*)d_ws + WFRAG_B + XFRAG_B);
        partial = (bf16*)((char*)d_ws + WFRAG_B + XFRAG_B + VS_B);
    } else {
        useFrag = 0;
        size_t avail = (ws_size > VS_B) ? (ws_size - VS_B) / (SLICE * 2) : 1;
        P = (int)avail; if (P < 1) P = 1; if (P > 128) P = 128;
        vsum    = (float*)d_ws;
        partial = (bf16*)((char*)d_ws + VS_B);
    }
    const int Jc = (JJ + P - 1) / P;
    const int RB = (P * 128 + 255) / 256;   // reduce blocks: P*128 groups... fixed 8192 threads
    (void)RB;

    if (useFrag) {
        prep_w<<<dim3(16384), dim3(256), 0, stream>>>(Wg, Wfrag);
        prep_x<<<dim3(1024),  dim3(256), 0, stream>>>(X,  Xfrag);
        caps_init<1><<<dim3(P, 4), dim3(1024), 0, stream>>>(Xfrag, Wfrag, X, Wg, partial, Jc);
        caps_reduce3<<<dim3(32), dim3(256), 0, stream>>>(partial, vsum, out, P, 0, 0);
        caps_route<1><<<dim3(P, 4), dim3(1024), 0, stream>>>(Xfrag, Wfrag, X, Wg, vsum, partial, Jc);
        caps_reduce3<<<dim3(32), dim3(256), 0, stream>>>(partial, vsum, out, P, 1, 0);
        caps_route<1><<<dim3(P, 4), dim3(1024), 0, stream>>>(Xfrag, Wfrag, X, Wg, vsum, partial, Jc);
        caps_reduce3<<<dim3(32), dim3(256), 0, stream>>>(partial, vsum, out, P, 2, 1);
    } else {
        caps_init<0><<<dim3(P, 4), dim3(1024), 0, stream>>>(Xfrag, Wfrag, X, Wg, partial, Jc);
        caps_reduce3<<<dim3(32), dim3(256), 0, stream>>>(partial, vsum, out, P, 0, 0);
        caps_route<0><<<dim3(P, 4), dim3(1024), 0, stream>>>(Xfrag, Wfrag, X, Wg, vsum, partial, Jc);
        caps_reduce3<<<dim3(32), dim3(256), 0, stream>>>(partial, vsum, out, P, 1, 0);
        caps_route<0><<<dim3(P, 4), dim3(1024), 0, stream>>>(Xfrag, Wfrag, X, Wg, vsum, partial, Jc);
        caps_reduce3<<<dim3(32), dim3(256), 0, stream>>>(partial, vsum, out, P, 2, 1);
    }
}